// Round 9
// baseline (815.088 us; speedup 1.0000x reference)
//
#include <hip/hip_runtime.h>

#define NN 50000
#define EE 800000

typedef __bf16 bf16x8 __attribute__((ext_vector_type(8)));
typedef float  f32x4  __attribute__((ext_vector_type(4)));

__device__ __forceinline__ float bf2f(ushort u) {
    union { unsigned int i; float f; } v; v.i = ((unsigned int)u) << 16; return v.f;
}
__device__ __forceinline__ ushort f2bf(float f) {        // RNE
    union { float f; unsigned int i; } v; v.f = f;
    unsigned int u = v.i;
    return (ushort)((u + 0x7FFFu + ((u >> 16) & 1u)) >> 16);
}
__device__ __forceinline__ ushort f2bf_fast(float f) {
    union { float f; unsigned int i; } v; v.f = f;
    return (ushort)((v.i + 0x8000u) >> 16);
}
__device__ __forceinline__ float silu(float x) { return x / (1.0f + __expf(-x)); }

// ---------------------------------------------------------------------------
// Dtype detection (0 = bf16 inputs, 1 = f32 inputs).
// ---------------------------------------------------------------------------
__global__ void detect_kernel(const ushort* __restrict__ xzu, int* __restrict__ flag) {
    __shared__ int cnt;
    if (threadIdx.x == 0) cnt = 0;
    __syncthreads();
    float v = bf2f(xzu[2 * threadIdx.x]);
    bool sane = (v == v) && (fabsf(v) <= 4.0f);
    if (sane) atomicAdd(&cnt, 1);
    __syncthreads();
    if (threadIdx.x == 0) *flag = (cnt >= 192) ? 0 : 1;
}

// ---------------------------------------------------------------------------
// prep: [0,3125) h->bf16 (8/thread); [3125,3712) xz->f32; [3712,6837) degree
// ---------------------------------------------------------------------------
__global__ void prep_kernel(const void* __restrict__ hsrc, const void* __restrict__ xzsrc,
                            const int* __restrict__ erow, const int* __restrict__ flag,
                            ushort* __restrict__ hb, float* __restrict__ xzf,
                            int* __restrict__ cntI) {
    const bool isf = (*flag != 0);
    int b = blockIdx.x;
    if (b < 3125) {
        int i = (b * 256 + threadIdx.x) * 8;
        uint4 o;
        if (isf) {
            const float* s = (const float*)hsrc + i;
            float4 f0 = *(const float4*)s;
            float4 f1 = *(const float4*)(s + 4);
            o.x = (unsigned int)f2bf(f0.x) | ((unsigned int)f2bf(f0.y) << 16);
            o.y = (unsigned int)f2bf(f0.z) | ((unsigned int)f2bf(f0.w) << 16);
            o.z = (unsigned int)f2bf(f1.x) | ((unsigned int)f2bf(f1.y) << 16);
            o.w = (unsigned int)f2bf(f1.z) | ((unsigned int)f2bf(f1.w) << 16);
        } else {
            o = *(const uint4*)((const ushort*)hsrc + i);
        }
        *(uint4*)(hb + i) = o;
    } else if (b < 3712) {
        int i = (b - 3125) * 256 + threadIdx.x;
        if (i < NN * 3)
            xzf[i] = isf ? ((const float*)xzsrc)[i] : bf2f(((const ushort*)xzsrc)[i]);
    } else {
        int e = (b - 3712) * 256 + threadIdx.x;
        if (e < EE) atomicAdd(&cntI[erow[e]], 1);
    }
}

// exclusive scan of degree counts -> basep; basep[NN] = EE
__global__ void scan_kernel(const int* __restrict__ cntI, int* __restrict__ basep) {
    __shared__ int s[1024];
    __shared__ int carry;
    if (threadIdx.x == 0) carry = 0;
    __syncthreads();
    for (int c0 = 0; c0 < NN; c0 += 1024) {
        int i = c0 + threadIdx.x;
        int v = (i < NN) ? cntI[i] : 0;
        s[threadIdx.x] = v;
        __syncthreads();
        for (int d = 1; d < 1024; d <<= 1) {
            int t = (threadIdx.x >= (unsigned)d) ? s[threadIdx.x - d] : 0;
            __syncthreads();
            s[threadIdx.x] += t;
            __syncthreads();
        }
        if (i < NN) basep[i] = carry + s[threadIdx.x] - v;
        __syncthreads();
        if (threadIdx.x == 1023) carry += s[1023];
        __syncthreads();
    }
    if (threadIdx.x == 0) basep[NN] = EE;
}

// per-edge destination slot in the row-sorted message array
__global__ void wpos_kernel(const int* __restrict__ erow, const int* __restrict__ basep,
                            int* __restrict__ ctr, int* __restrict__ wpos) {
    int e = blockIdx.x * 256 + threadIdx.x;
    if (e < EE) {
        int r = erow[e];
        wpos[e] = basep[r] + atomicAdd(&ctr[r], 1);
    }
}

// ---------------------------------------------------------------------------
// swizzle (0..47) + misc (48): fb = [be1|be2|bn1|bn2|We1[256][:]]
// ---------------------------------------------------------------------------
__global__ void swizzle_misc_kernel(const void* We1, const void* We2,
                                    const void* Wn1, const void* Wn2,
                                    const void* be1, const void* be2,
                                    const void* bn1, const void* bn2,
                                    const int* __restrict__ flag,
                                    ushort* __restrict__ We1s, ushort* __restrict__ We2s,
                                    ushort* __restrict__ Wn1s, ushort* __restrict__ Wn2s,
                                    float* __restrict__ fb) {
    const bool isf = (*flag != 0);
    if (blockIdx.x == 48) {
        for (int j = threadIdx.x; j < 640; j += 256) {
            int which = j >> 7, k = j & 127;
            const void* src = (which == 0) ? be1 : (which == 1) ? be2 :
                              (which == 2) ? bn1 : (which == 3) ? bn2 : We1;
            size_t idx = (which == 4) ? ((size_t)256 * 128 + k) : (size_t)k;
            fb[j] = isf ? ((const float*)src)[idx] : bf2f(((const ushort*)src)[idx]);
        }
        return;
    }
    int c = blockIdx.x * 256 + threadIdx.x;
    const void* src; ushort* dst; int cl;
    if      (c <  4096) { src = We1; dst = We1s; cl = c;         }
    else if (c <  6144) { src = We2; dst = We2s; cl = c - 4096;  }
    else if (c < 10240) { src = Wn1; dst = Wn1s; cl = c - 6144;  }
    else                { src = Wn2; dst = Wn2s; cl = c - 10240; }
    int l = cl & 63, nt = (cl >> 6) & 7, kc = cl >> 9;
    int kbase = kc * 32 + (l >> 4) * 8;
    int n = nt * 16 + (l & 15);
    ushort tmp[8];
#pragma unroll
    for (int j = 0; j < 8; ++j) {
        size_t idx = (size_t)(kbase + j) * 128 + n;
        tmp[j] = isf ? f2bf(((const float*)src)[idx]) : ((const ushort*)src)[idx];
    }
#pragma unroll
    for (int j = 0; j < 8; ++j) dst[(size_t)cl * 8 + j] = tmp[j];
}

// ---------------------------------------------------------------------------
// Edge kernel (r4 gather structure, NO atomics): 64-edge tiles, 4 waves.
//   m2 = silu(m1@We2+be2) -> LDS (XOR-swizzled, reuses sA) -> coalesced 16B
//   stores into destination-sorted m2s[wpos[e]][:].
// ---------------------------------------------------------------------------
__global__ __launch_bounds__(256, 3) void edge_kernel(
    const ushort* __restrict__ hb, const float* __restrict__ xzf,
    const int* __restrict__ erow, const int* __restrict__ ecol,
    const int* __restrict__ wpos,
    const ushort* __restrict__ We1s, const ushort* __restrict__ We2s,
    const float* __restrict__ fb, ushort* __restrict__ m2s) {
    __shared__ __align__(16) ushort sA[16384];   // 32KB: A-frags, later m2 rows
    __shared__ __align__(16) ushort sM[8192];    // 16KB: m1 frags
    __shared__ float sDist[64];
    __shared__ int   sWpos[64];

    const int tid = threadIdx.x;
    const int lane = tid & 63, w = tid >> 6;
    const int col = lane & 15, quad = lane >> 4;
    const int nt0 = w * 2;

    const int nA = w * 32 + col, nB = nA + 16;
    const float be1A = fb[nA],       be1B = fb[nB];
    const float be2A = fb[128 + nA], be2B = fb[128 + nB];
    const float wlA  = fb[512 + nA], wlB  = fb[512 + nB];

    // We2 B-fragments in registers
    bf16x8 B2[8];
#pragma unroll
    for (int kc = 0; kc < 4; ++kc) {
        B2[kc * 2]     = *(const bf16x8*)(We2s + ((kc * 8 + nt0)     * 64 + lane) * 8);
        B2[kc * 2 + 1] = *(const bf16x8*)(We2s + ((kc * 8 + nt0 + 1) * 64 + lane) * 8);
    }

    for (int tile = blockIdx.x; tile < EE / 64; tile += gridDim.x) {
        __syncthreads();   // protect sA(m2)/sM/meta vs previous iteration
        const int e0 = tile * 64;
        if (tid < 64) {
            int e = e0 + tid;
            int r = erow[e], c = ecol[e];
            sWpos[tid] = wpos[e];
            float x1 = xzf[3 * r], y1 = xzf[3 * r + 1], z1 = xzf[3 * r + 2];
            float x2 = xzf[3 * c], y2 = xzf[3 * c + 1], z2 = xzf[3 * c + 2];
            float dx = x1 - x2, dy = y1 - y2, dz = z1 - z2;
            float u = (dx * dx + dy * dy + dz * dz) / (2.0f * z1 * z2);
            u = fminf(fmaxf(u, 0.0f), 1.0e6f);
            sDist[tid] = __logf(1.0f + u + sqrtf(u * (u + 2.0f)));
        }
        // r4 staging pattern (best measured FETCH)
#pragma unroll
        for (int i = 0; i < 8; ++i) {
            int cidx = tid + i * 256;
            int m = cidx & 63, kb = cidx >> 6;
            int e = e0 + m;
            int src_node = (kb < 16) ? erow[e] : ecol[e];
            int k0 = (kb & 15) * 8;
            uint4 v = *(const uint4*)(hb + (size_t)src_node * 128 + k0);
            int g = m >> 4, ml = m & 15, kc = kb >> 2, q = kb & 3;
            *(uint4*)(sA + ((g * 8 + kc) * 64 + q * 16 + ml) * 8) = v;
        }
        __syncthreads();   // BARRIER-A

        // ---- GEMM1: [64,256] @ We1 ----
        f32x4 acc[4][2] = {};
#pragma unroll
        for (int kc = 0; kc < 8; ++kc) {
            bf16x8 b0 = *(const bf16x8*)(We1s + ((kc * 8 + nt0)     * 64 + lane) * 8);
            bf16x8 b1 = *(const bf16x8*)(We1s + ((kc * 8 + nt0 + 1) * 64 + lane) * 8);
#pragma unroll
            for (int g = 0; g < 4; ++g) {
                bf16x8 a = *(const bf16x8*)(sA + ((g * 8 + kc) * 64 + lane) * 8);
                acc[g][0] = __builtin_amdgcn_mfma_f32_16x16x32_bf16(a, b0, acc[g][0], 0, 0, 0);
                acc[g][1] = __builtin_amdgcn_mfma_f32_16x16x32_bf16(a, b1, acc[g][1], 0, 0, 0);
            }
        }
        // ep1 -> sM (A-frag order)
#pragma unroll
        for (int g = 0; g < 4; ++g) {
            int base0 = ((g * 4 + w) * 64 + (col >> 3) * 16) * 8 + (col & 7);
#pragma unroll
            for (int r = 0; r < 4; ++r) {
                int mrow = quad * 4 + r;
                float d = sDist[g * 16 + mrow];
                sM[base0 + mrow * 8]              = f2bf_fast(silu(acc[g][0][r] + d * wlA + be1A));
                sM[base0 + 2 * 16 * 8 + mrow * 8] = f2bf_fast(silu(acc[g][1][r] + d * wlB + be1B));
            }
        }
        __syncthreads();   // BARRIER-B (all sA reads done -> reuse as m2 buffer)

        // ---- GEMM2: m1 @ We2 (B in regs) ----
        f32x4 acc2[4][2] = {};
#pragma unroll
        for (int kc = 0; kc < 4; ++kc) {
#pragma unroll
            for (int g = 0; g < 4; ++g) {
                bf16x8 a = *(const bf16x8*)(sM + ((g * 4 + kc) * 64 + lane) * 8);
                acc2[g][0] = __builtin_amdgcn_mfma_f32_16x16x32_bf16(a, B2[kc * 2],     acc2[g][0], 0, 0, 0);
                acc2[g][1] = __builtin_amdgcn_mfma_f32_16x16x32_bf16(a, B2[kc * 2 + 1], acc2[g][1], 0, 0, 0);
            }
        }
        // ep2: silu -> m2 rows in sA (row-major, chunk slot XOR (m&7))
        ushort* sP = sA;
#pragma unroll
        for (int g = 0; g < 4; ++g) {
#pragma unroll
            for (int r = 0; r < 4; ++r) {
                int m = g * 16 + quad * 4 + r;
                int sa = ((nA >> 3) ^ (m & 7)) * 8 + (nA & 7);
                int sb = ((nB >> 3) ^ (m & 7)) * 8 + (nB & 7);
                sP[m * 128 + sa] = f2bf_fast(silu(acc2[g][0][r] + be2A));
                sP[m * 128 + sb] = f2bf_fast(silu(acc2[g][1][r] + be2B));
            }
        }
        __syncthreads();   // BARRIER-C: m2 rows complete

        // scatter: 1024 16B chunks; 16 lanes cover one 256B row (coalesced)
#pragma unroll
        for (int i = 0; i < 4; ++i) {
            int cidx = tid + i * 256;
            int m = cidx >> 4, ch = cidx & 15;
            int slot = ch ^ (m & 7);
            uint4 v = *(const uint4*)(sP + m * 128 + slot * 8);
            *(uint4*)(m2s + (size_t)sWpos[m] * 128 + ch * 8) = v;
        }
    }
}

// ---------------------------------------------------------------------------
// agg: reduce each node's contiguous message block -> bf16 aggb (mean)
// thread = (node, 16B-chunk): sequential 256B-row reads, coalesced stores.
// ---------------------------------------------------------------------------
__global__ __launch_bounds__(256) void agg_kernel(
    const ushort* __restrict__ m2s, const int* __restrict__ basep,
    ushort* __restrict__ aggb) {
    int id = blockIdx.x * 256 + threadIdx.x;
    int node = id >> 4, ch = id & 15;
    if (node >= NN) return;
    int b = basep[node], e = basep[node + 1];
    float s[8] = {0, 0, 0, 0, 0, 0, 0, 0};
    for (int d = b; d < e; ++d) {
        uint4 v = *(const uint4*)(m2s + (size_t)d * 128 + ch * 8);
        unsigned int wds[4] = {v.x, v.y, v.z, v.w};
#pragma unroll
        for (int j = 0; j < 4; ++j) {
            union { unsigned int i; float f; } lo, hi;
            lo.i = wds[j] << 16;
            hi.i = wds[j] & 0xFFFF0000u;
            s[2 * j] += lo.f;
            s[2 * j + 1] += hi.f;
        }
    }
    float inv = 1.0f / (float)((e - b) > 1 ? (e - b) : 1);
    uint4 o;
    o.x = (unsigned int)f2bf_fast(s[0] * inv) | ((unsigned int)f2bf_fast(s[1] * inv) << 16);
    o.y = (unsigned int)f2bf_fast(s[2] * inv) | ((unsigned int)f2bf_fast(s[3] * inv) << 16);
    o.z = (unsigned int)f2bf_fast(s[4] * inv) | ((unsigned int)f2bf_fast(s[5] * inv) << 16);
    o.w = (unsigned int)f2bf_fast(s[6] * inv) | ((unsigned int)f2bf_fast(s[7] * inv) << 16);
    *(uint4*)(aggb + (size_t)node * 128 + ch * 8) = o;
}

// ---------------------------------------------------------------------------
// Node kernel: z = [h | aggb]; out = h + silu(z@Wn1+bn1)@Wn2+bn2
// ---------------------------------------------------------------------------
__global__ __launch_bounds__(256, 3) void node_kernel(
    const ushort* __restrict__ hb, const void* __restrict__ hraw,
    const ushort* __restrict__ aggb,
    const ushort* __restrict__ Wn1s, const ushort* __restrict__ Wn2s,
    const float* __restrict__ fb, const int* __restrict__ flag,
    void* __restrict__ outv) {
    __shared__ __align__(16) ushort sA[16384];
    __shared__ __align__(16) ushort sM[8192];
    const int tid = threadIdx.x;
    const int lane = tid & 63, w = tid >> 6;
    const int col = lane & 15, quad = lane >> 4;
    const int nt0 = w * 2;
    const int ntiles = (NN + 63) / 64;
    const bool isf = (*flag != 0);
    float* outf = (float*)outv;
    ushort* outu = (ushort*)outv;

    const int nA = w * 32 + col, nB = nA + 16;
    const float bn1A = fb[256 + nA], bn1B = fb[256 + nB];
    const float bn2A = fb[384 + nA], bn2B = fb[384 + nB];

    for (int tile = blockIdx.x; tile < ntiles; tile += gridDim.x) {
        __syncthreads();
        const int n0 = tile * 64;
#pragma unroll
        for (int i = 0; i < 8; ++i) {
            int kb = w + 4 * i;
            int node = n0 + lane;
            uint4 v;
            if (node < NN) {
                const ushort* src = (kb < 16) ? (hb + (size_t)node * 128 + kb * 8)
                                              : (aggb + (size_t)node * 128 + (kb - 16) * 8);
                v = *(const uint4*)src;
            } else {
                v = make_uint4(0, 0, 0, 0);
            }
            *(uint4*)(sA + (((quad * 8 + i) * 64) + w * 16 + col) * 8) = v;
        }
        __syncthreads();

        f32x4 acc[4][2] = {};
#pragma unroll
        for (int kc = 0; kc < 8; ++kc) {
            bf16x8 b0 = *(const bf16x8*)(Wn1s + ((kc * 8 + nt0)     * 64 + lane) * 8);
            bf16x8 b1 = *(const bf16x8*)(Wn1s + ((kc * 8 + nt0 + 1) * 64 + lane) * 8);
#pragma unroll
            for (int g = 0; g < 4; ++g) {
                bf16x8 a = *(const bf16x8*)(sA + ((g * 8 + kc) * 64 + lane) * 8);
                acc[g][0] = __builtin_amdgcn_mfma_f32_16x16x32_bf16(a, b0, acc[g][0], 0, 0, 0);
                acc[g][1] = __builtin_amdgcn_mfma_f32_16x16x32_bf16(a, b1, acc[g][1], 0, 0, 0);
            }
        }
#pragma unroll
        for (int g = 0; g < 4; ++g) {
            int base0 = ((g * 4 + w) * 64 + (col >> 3) * 16) * 8 + (col & 7);
#pragma unroll
            for (int r = 0; r < 4; ++r) {
                int mrow = quad * 4 + r;
                sM[base0 + mrow * 8]              = f2bf_fast(silu(acc[g][0][r] + bn1A));
                sM[base0 + 2 * 16 * 8 + mrow * 8] = f2bf_fast(silu(acc[g][1][r] + bn1B));
            }
        }
        __syncthreads();

        f32x4 acc2[4][2] = {};
#pragma unroll
        for (int kc = 0; kc < 4; ++kc) {
            bf16x8 b0 = *(const bf16x8*)(Wn2s + ((kc * 8 + nt0)     * 64 + lane) * 8);
            bf16x8 b1 = *(const bf16x8*)(Wn2s + ((kc * 8 + nt0 + 1) * 64 + lane) * 8);
#pragma unroll
            for (int g = 0; g < 4; ++g) {
                bf16x8 a = *(const bf16x8*)(sM + ((g * 4 + kc) * 64 + lane) * 8);
                acc2[g][0] = __builtin_amdgcn_mfma_f32_16x16x32_bf16(a, b0, acc2[g][0], 0, 0, 0);
                acc2[g][1] = __builtin_amdgcn_mfma_f32_16x16x32_bf16(a, b1, acc2[g][1], 0, 0, 0);
            }
        }
#pragma unroll
        for (int g = 0; g < 4; ++g) {
#pragma unroll
            for (int r = 0; r < 4; ++r) {
                int ml2 = g * 16 + quad * 4 + r;
                int node = n0 + ml2;
                if (node < NN) {
                    size_t oi = (size_t)node * 128;
                    float h0 = isf ? ((const float*)hraw)[oi + nA] : bf2f(((const ushort*)hraw)[oi + nA]);
                    float h1 = isf ? ((const float*)hraw)[oi + nB] : bf2f(((const ushort*)hraw)[oi + nB]);
                    float x0 = acc2[g][0][r] + bn2A + h0;
                    float x1 = acc2[g][1][r] + bn2B + h1;
                    if (isf) { outf[oi + nA] = x0; outf[oi + nB] = x1; }
                    else     { outu[oi + nA] = f2bf_fast(x0); outu[oi + nB] = f2bf_fast(x1); }
                }
            }
        }
    }
}

extern "C" void kernel_launch(void* const* d_in, const int* in_sizes, int n_in,
                              void* d_out, int out_size, void* d_ws, size_t ws_size,
                              hipStream_t stream) {
    const void* xz  = d_in[0];
    const void* h   = d_in[1];
    const void* We1 = d_in[2];
    const void* be1 = d_in[3];
    const void* We2 = d_in[4];
    const void* be2 = d_in[5];
    const void* Wn1 = d_in[6];
    const void* bn1 = d_in[7];
    const void* Wn2 = d_in[8];
    const void* bn2 = d_in[9];
    const int*  ei  = (const int*)d_in[10];
    const int* erow = ei;
    const int* ecol = ei + EE;

    char* base = (char*)d_ws;
    size_t cur = 0;
    auto alloc = [&](size_t bytes) { size_t o = cur; cur = (cur + bytes + 255) & ~(size_t)255; return o; };
    int*    flag = (int*)   (base + alloc(16));
    int*    cntI = (int*)   (base + alloc((size_t)NN * 4));
    int*    ctr  = (int*)   (base + alloc((size_t)NN * 4));
    int*    basep= (int*)   (base + alloc((size_t)(NN + 1) * 4));
    int*    wpos = (int*)   (base + alloc((size_t)EE * 4));
    ushort* m2s  = (ushort*)(base + alloc((size_t)EE * 128 * 2));   // 204.8 MB
    ushort* hb   = (ushort*)(base + alloc((size_t)NN * 128 * 2));
    ushort* aggb = (ushort*)(base + alloc((size_t)NN * 128 * 2));
    float*  xzf  = (float*) (base + alloc((size_t)NN * 3 * 4));
    ushort* We1s = (ushort*)(base + alloc(32768 * 2));
    ushort* We2s = (ushort*)(base + alloc(16384 * 2));
    ushort* Wn1s = (ushort*)(base + alloc(32768 * 2));
    ushort* Wn2s = (ushort*)(base + alloc(16384 * 2));
    float*  fb   = (float*) (base + alloc(640 * 4));

    // zero cntI + ctr (adjacent)
    size_t zbytes = (size_t)((char*)basep - (char*)cntI);
    (void)hipMemsetAsync(cntI, 0, zbytes, stream);

    detect_kernel<<<1, 256, 0, stream>>>((const ushort*)xz, flag);
    prep_kernel<<<6837, 256, 0, stream>>>(h, xz, erow, flag, hb, xzf, cntI);
    scan_kernel<<<1, 1024, 0, stream>>>(cntI, basep);
    wpos_kernel<<<(EE + 255) / 256, 256, 0, stream>>>(erow, basep, ctr, wpos);
    swizzle_misc_kernel<<<49, 256, 0, stream>>>(We1, We2, Wn1, Wn2, be1, be2, bn1, bn2,
                                                flag, We1s, We2s, Wn1s, Wn2s, fb);
    edge_kernel<<<768, 256, 0, stream>>>(hb, xzf, erow, ecol, wpos, We1s, We2s, fb, m2s);
    agg_kernel<<<(NN * 16 + 255) / 256, 256, 0, stream>>>(m2s, basep, aggb);
    node_kernel<<<782, 256, 0, stream>>>(hb, h, aggb, Wn1s, Wn2s, fb, flag, d_out);
}

// Round 10
// 540.473 us; speedup vs baseline: 1.5081x; 1.5081x over previous
//
#include <hip/hip_runtime.h>

#define NN 50000
#define EE 800000

typedef __bf16 bf16x8 __attribute__((ext_vector_type(8)));
typedef float  f32x4  __attribute__((ext_vector_type(4)));

__device__ __forceinline__ float bf2f(ushort u) {
    union { unsigned int i; float f; } v; v.i = ((unsigned int)u) << 16; return v.f;
}
__device__ __forceinline__ ushort f2bf(float f) {        // RNE
    union { float f; unsigned int i; } v; v.f = f;
    unsigned int u = v.i;
    return (ushort)((u + 0x7FFFu + ((u >> 16) & 1u)) >> 16);
}
__device__ __forceinline__ ushort f2bf_fast(float f) {
    union { float f; unsigned int i; } v; v.f = f;
    return (ushort)((v.i + 0x8000u) >> 16);
}
__device__ __forceinline__ float silu(float x) { return x / (1.0f + __expf(-x)); }

// ---------------------------------------------------------------------------
__global__ void detect_kernel(const ushort* __restrict__ xzu, int* __restrict__ flag) {
    __shared__ int cnt;
    if (threadIdx.x == 0) cnt = 0;
    __syncthreads();
    float v = bf2f(xzu[2 * threadIdx.x]);
    bool sane = (v == v) && (fabsf(v) <= 4.0f);
    if (sane) atomicAdd(&cnt, 1);
    __syncthreads();
    if (threadIdx.x == 0) *flag = (cnt >= 192) ? 0 : 1;
}

// ---------------------------------------------------------------------------
// prep: [0,3125) h->bf16 (8/thread); [3125,3712) xz->f32; [3712,6837) degree
// ---------------------------------------------------------------------------
__global__ void prep_kernel(const void* __restrict__ hsrc, const void* __restrict__ xzsrc,
                            const int* __restrict__ erow, const int* __restrict__ flag,
                            ushort* __restrict__ hb, float* __restrict__ xzf,
                            int* __restrict__ cntI) {
    const bool isf = (*flag != 0);
    int b = blockIdx.x;
    if (b < 3125) {
        int i = (b * 256 + threadIdx.x) * 8;
        uint4 o;
        if (isf) {
            const float* s = (const float*)hsrc + i;
            float4 f0 = *(const float4*)s;
            float4 f1 = *(const float4*)(s + 4);
            o.x = (unsigned int)f2bf(f0.x) | ((unsigned int)f2bf(f0.y) << 16);
            o.y = (unsigned int)f2bf(f0.z) | ((unsigned int)f2bf(f0.w) << 16);
            o.z = (unsigned int)f2bf(f1.x) | ((unsigned int)f2bf(f1.y) << 16);
            o.w = (unsigned int)f2bf(f1.z) | ((unsigned int)f2bf(f1.w) << 16);
        } else {
            o = *(const uint4*)((const ushort*)hsrc + i);
        }
        *(uint4*)(hb + i) = o;
    } else if (b < 3712) {
        int i = (b - 3125) * 256 + threadIdx.x;
        if (i < NN * 3)
            xzf[i] = isf ? ((const float*)xzsrc)[i] : bf2f(((const ushort*)xzsrc)[i]);
    } else {
        int e = (b - 3712) * 256 + threadIdx.x;
        if (e < EE) atomicAdd(&cntI[erow[e]], 1);
    }
}

// ---------------------------------------------------------------------------
// swizzle (0..47) + misc (48): fb=[be1|be2|bn1|bn2|We1[256][:]], wlb=bf16 copy
// ---------------------------------------------------------------------------
__global__ void swizzle_misc_kernel(const void* We1, const void* We2,
                                    const void* Wn1, const void* Wn2,
                                    const void* be1, const void* be2,
                                    const void* bn1, const void* bn2,
                                    const int* __restrict__ flag,
                                    ushort* __restrict__ We1s, ushort* __restrict__ We2s,
                                    ushort* __restrict__ Wn1s, ushort* __restrict__ Wn2s,
                                    float* __restrict__ fb, ushort* __restrict__ wlb) {
    const bool isf = (*flag != 0);
    if (blockIdx.x == 48) {
        for (int j = threadIdx.x; j < 640; j += 256) {
            int which = j >> 7, k = j & 127;
            const void* src = (which == 0) ? be1 : (which == 1) ? be2 :
                              (which == 2) ? bn1 : (which == 3) ? bn2 : We1;
            size_t idx = (which == 4) ? ((size_t)256 * 128 + k) : (size_t)k;
            float v = isf ? ((const float*)src)[idx] : bf2f(((const ushort*)src)[idx]);
            fb[j] = v;
            if (which == 4) wlb[k] = f2bf(v);
        }
        return;
    }
    int c = blockIdx.x * 256 + threadIdx.x;
    const void* src; ushort* dst; int cl;
    if      (c <  4096) { src = We1; dst = We1s; cl = c;         }
    else if (c <  6144) { src = We2; dst = We2s; cl = c - 4096;  }
    else if (c < 10240) { src = Wn1; dst = Wn1s; cl = c - 6144;  }
    else                { src = Wn2; dst = Wn2s; cl = c - 10240; }
    int l = cl & 63, nt = (cl >> 6) & 7, kc = cl >> 9;
    int kbase = kc * 32 + (l >> 4) * 8;
    int n = nt * 16 + (l & 15);
    ushort tmp[8];
#pragma unroll
    for (int j = 0; j < 8; ++j) {
        size_t idx = (size_t)(kbase + j) * 128 + n;
        tmp[j] = isf ? f2bf(((const float*)src)[idx]) : ((const ushort*)src)[idx];
    }
#pragma unroll
    for (int j = 0; j < 8; ++j) dst[(size_t)cl * 8 + j] = tmp[j];
}

// ---------------------------------------------------------------------------
// pq: P' = h@We1[0:128]+be1, Q = h@We1[128:256]  (both bf16, row-major)
// ---------------------------------------------------------------------------
__global__ __launch_bounds__(256, 3) void pq_kernel(
    const ushort* __restrict__ hb, const ushort* __restrict__ We1s,
    const float* __restrict__ fb, ushort* __restrict__ Pp, ushort* __restrict__ Qq) {
    __shared__ __align__(16) ushort sA[8192];   // 16KB: h A-frags (K=128)
    const int tid = threadIdx.x;
    const int lane = tid & 63, w = tid >> 6;
    const int col = lane & 15, quad = lane >> 4;
    const int nt0 = w * 2;
    const int ntiles = (NN + 63) / 64;
    const int nA = w * 32 + col, nB = nA + 16;
    const float be1A = fb[nA], be1B = fb[nB];

    for (int tile = blockIdx.x; tile < ntiles; tile += gridDim.x) {
        __syncthreads();
        const int n0 = tile * 64;
#pragma unroll
        for (int i = 0; i < 4; ++i) {
            int node = n0 + lane;
            uint4 v = (node < NN) ? *(const uint4*)(hb + (size_t)node * 128 + (w + 4 * i) * 8)
                                  : make_uint4(0, 0, 0, 0);
            // g=lane>>4, ml=lane&15, kc=i, q=w
            *(uint4*)(sA + (((lane >> 4) * 4 + i) * 64 + w * 16 + (lane & 15)) * 8) = v;
        }
        __syncthreads();

        f32x4 accP[4][2] = {}, accQ[4][2] = {};
#pragma unroll
        for (int kc = 0; kc < 4; ++kc) {
            bf16x8 bp0 = *(const bf16x8*)(We1s + ((kc * 8 + nt0)           * 64 + lane) * 8);
            bf16x8 bp1 = *(const bf16x8*)(We1s + ((kc * 8 + nt0 + 1)       * 64 + lane) * 8);
            bf16x8 bq0 = *(const bf16x8*)(We1s + (((kc + 4) * 8 + nt0)     * 64 + lane) * 8);
            bf16x8 bq1 = *(const bf16x8*)(We1s + (((kc + 4) * 8 + nt0 + 1) * 64 + lane) * 8);
#pragma unroll
            for (int g = 0; g < 4; ++g) {
                bf16x8 a = *(const bf16x8*)(sA + ((g * 4 + kc) * 64 + lane) * 8);
                accP[g][0] = __builtin_amdgcn_mfma_f32_16x16x32_bf16(a, bp0, accP[g][0], 0, 0, 0);
                accP[g][1] = __builtin_amdgcn_mfma_f32_16x16x32_bf16(a, bp1, accP[g][1], 0, 0, 0);
                accQ[g][0] = __builtin_amdgcn_mfma_f32_16x16x32_bf16(a, bq0, accQ[g][0], 0, 0, 0);
                accQ[g][1] = __builtin_amdgcn_mfma_f32_16x16x32_bf16(a, bq1, accQ[g][1], 0, 0, 0);
            }
        }
#pragma unroll
        for (int g = 0; g < 4; ++g) {
#pragma unroll
            for (int r = 0; r < 4; ++r) {
                int node = n0 + g * 16 + quad * 4 + r;
                if (node < NN) {
                    size_t o = (size_t)node * 128;
                    Pp[o + nA] = f2bf(accP[g][0][r] + be1A);
                    Pp[o + nB] = f2bf(accP[g][1][r] + be1B);
                    Qq[o + nA] = f2bf(accQ[g][0][r]);
                    Qq[o + nB] = f2bf(accQ[g][1][r]);
                }
            }
        }
    }
}

// ---------------------------------------------------------------------------
// dist: per-edge AdS distance (f32)
// ---------------------------------------------------------------------------
__global__ void dist_kernel(const int* __restrict__ erow, const int* __restrict__ ecol,
                            const float* __restrict__ xzf, float* __restrict__ dist) {
    int e = blockIdx.x * 256 + threadIdx.x;
    if (e >= EE) return;
    int r = erow[e], c = ecol[e];
    float4 a = *(const float4*)(xzf + 3 * r);   // xzf padded by 4 floats
    float4 b = *(const float4*)(xzf + 3 * c);
    float dx = a.x - b.x, dy = a.y - b.y, dz = a.z - b.z;
    float u = (dx * dx + dy * dy + dz * dz) / (2.0f * a.z * b.z);
    u = fminf(fmaxf(u, 0.0f), 1.0e6f);
    dist[e] = __logf(1.0f + u + sqrtf(u * (u + 2.0f)));
}

// ---------------------------------------------------------------------------
// Edge kernel (no GEMM1): per 64-edge tile
//   m1[m][ch*8+j] = silu(P'[row][..] + Q[col][..] + d*wl[..])  -> sM (A-frag)
//   m2 = silu(m1@We2+be2) -> atomics into agg[row]
// Thread (w,lane): edge m=lane, chunks ch=w+4i.
// ---------------------------------------------------------------------------
__global__ __launch_bounds__(256, 4) void edge_kernel(
    const ushort* __restrict__ Pp, const ushort* __restrict__ Qq,
    const int* __restrict__ erow, const int* __restrict__ ecol,
    const float* __restrict__ dist, const ushort* __restrict__ We2s,
    const ushort* __restrict__ wlb, const float* __restrict__ fb,
    float* __restrict__ agg) {
    __shared__ __align__(16) ushort sM[8192];   // 16KB: m1 A-frags
    __shared__ int sRowIdx[64];

    const int tid = threadIdx.x;
    const int lane = tid & 63, w = tid >> 6;
    const int col = lane & 15, quad = lane >> 4;
    const int nt0 = w * 2;

    const int nA = w * 32 + col, nB = nA + 16;
    const float be2A = fb[128 + nA], be2B = fb[128 + nB];

    // loop-invariant: We2 B-frags + wl chunks (ch = w+4i)
    bf16x8 B2[8];
#pragma unroll
    for (int kc = 0; kc < 4; ++kc) {
        B2[kc * 2]     = *(const bf16x8*)(We2s + ((kc * 8 + nt0)     * 64 + lane) * 8);
        B2[kc * 2 + 1] = *(const bf16x8*)(We2s + ((kc * 8 + nt0 + 1) * 64 + lane) * 8);
    }
    bf16x8 WL[4];
#pragma unroll
    for (int i = 0; i < 4; ++i) WL[i] = *(const bf16x8*)(wlb + (w + 4 * i) * 8);

    for (int tile = blockIdx.x; tile < EE / 64; tile += gridDim.x) {
        __syncthreads();   // protect sM/sRowIdx vs previous iteration's readers
        const int e0 = tile * 64;
        const int e = e0 + lane;
        const int r = erow[e], c = ecol[e];
        const float d = dist[e];
        if (w == 0) sRowIdx[lane] = r;
        // m1 chunks ch = w+4i for edge m=lane
#pragma unroll
        for (int i = 0; i < 4; ++i) {
            int ch = w + 4 * i;
            bf16x8 p = *(const bf16x8*)(Pp + (size_t)r * 128 + ch * 8);
            bf16x8 q = *(const bf16x8*)(Qq + (size_t)c * 128 + ch * 8);
            ushort out8[8];
#pragma unroll
            for (int j = 0; j < 8; ++j) {
                float x = (float)p[j] + (float)q[j] + d * (float)WL[i][j];
                out8[j] = f2bf_fast(silu(x));
            }
            // slot: g=lane>>4, ml=lane&15, kc=i, q=w
            *(uint4*)(sM + (((lane >> 4) * 4 + i) * 64 + w * 16 + (lane & 15)) * 8) =
                *(const uint4*)out8;
        }
        __syncthreads();   // sM ready

        // ---- GEMM2: m1[64,128] @ We2 (B in regs) ----
        f32x4 acc2[4][2] = {};
#pragma unroll
        for (int kc = 0; kc < 4; ++kc) {
#pragma unroll
            for (int g = 0; g < 4; ++g) {
                bf16x8 a = *(const bf16x8*)(sM + ((g * 4 + kc) * 64 + lane) * 8);
                acc2[g][0] = __builtin_amdgcn_mfma_f32_16x16x32_bf16(a, B2[kc * 2],     acc2[g][0], 0, 0, 0);
                acc2[g][1] = __builtin_amdgcn_mfma_f32_16x16x32_bf16(a, B2[kc * 2 + 1], acc2[g][1], 0, 0, 0);
            }
        }
        // ep2: silu(+be2) -> atomics into agg[row]
#pragma unroll
        for (int g = 0; g < 4; ++g) {
#pragma unroll
            for (int r4 = 0; r4 < 4; ++r4) {
                int m = g * 16 + quad * 4 + r4;
                int row = sRowIdx[m];
                unsafeAtomicAdd(&agg[(size_t)row * 128 + nA], silu(acc2[g][0][r4] + be2A));
                unsafeAtomicAdd(&agg[(size_t)row * 128 + nB], silu(acc2[g][1][r4] + be2B));
            }
        }
    }
}

// ---------------------------------------------------------------------------
// Node kernel: z = [h | agg/max(cnt,1)]; out = h + silu(z@Wn1+bn1)@Wn2+bn2
// ---------------------------------------------------------------------------
__global__ __launch_bounds__(256, 3) void node_kernel(
    const ushort* __restrict__ hb, const void* __restrict__ hraw,
    const float* __restrict__ agg, const int* __restrict__ cntI,
    const ushort* __restrict__ Wn1s, const ushort* __restrict__ Wn2s,
    const float* __restrict__ fb, const int* __restrict__ flag,
    void* __restrict__ outv) {
    __shared__ __align__(16) ushort sA[16384];
    __shared__ __align__(16) ushort sM[8192];
    const int tid = threadIdx.x;
    const int lane = tid & 63, w = tid >> 6;
    const int col = lane & 15, quad = lane >> 4;
    const int nt0 = w * 2;
    const int ntiles = (NN + 63) / 64;
    const bool isf = (*flag != 0);
    float* outf = (float*)outv;
    ushort* outu = (ushort*)outv;

    const int nA = w * 32 + col, nB = nA + 16;
    const float bn1A = fb[256 + nA], bn1B = fb[256 + nB];
    const float bn2A = fb[384 + nA], bn2B = fb[384 + nB];

    for (int tile = blockIdx.x; tile < ntiles; tile += gridDim.x) {
        __syncthreads();
        const int n0 = tile * 64;
#pragma unroll
        for (int i = 0; i < 8; ++i) {
            int kb = w + 4 * i;
            int node = n0 + lane;
            uint4 v;
            if (node < NN) {
                if (kb < 16) {
                    v = *(const uint4*)(hb + (size_t)node * 128 + kb * 8);
                } else {
                    const float* ap = agg + (size_t)node * 128 + (kb - 16) * 8;
                    float invc = 1.0f / fmaxf((float)cntI[node], 1.0f);
                    float4 f0 = *(const float4*)ap;
                    float4 f1 = *(const float4*)(ap + 4);
                    v.x = (unsigned int)f2bf_fast(f0.x * invc) | ((unsigned int)f2bf_fast(f0.y * invc) << 16);
                    v.y = (unsigned int)f2bf_fast(f0.z * invc) | ((unsigned int)f2bf_fast(f0.w * invc) << 16);
                    v.z = (unsigned int)f2bf_fast(f1.x * invc) | ((unsigned int)f2bf_fast(f1.y * invc) << 16);
                    v.w = (unsigned int)f2bf_fast(f1.z * invc) | ((unsigned int)f2bf_fast(f1.w * invc) << 16);
                }
            } else {
                v = make_uint4(0, 0, 0, 0);
            }
            *(uint4*)(sA + (((quad * 8 + i) * 64) + w * 16 + col) * 8) = v;
        }
        __syncthreads();

        f32x4 acc[4][2] = {};
#pragma unroll
        for (int kc = 0; kc < 8; ++kc) {
            bf16x8 b0 = *(const bf16x8*)(Wn1s + ((kc * 8 + nt0)     * 64 + lane) * 8);
            bf16x8 b1 = *(const bf16x8*)(Wn1s + ((kc * 8 + nt0 + 1) * 64 + lane) * 8);
#pragma unroll
            for (int g = 0; g < 4; ++g) {
                bf16x8 a = *(const bf16x8*)(sA + ((g * 8 + kc) * 64 + lane) * 8);
                acc[g][0] = __builtin_amdgcn_mfma_f32_16x16x32_bf16(a, b0, acc[g][0], 0, 0, 0);
                acc[g][1] = __builtin_amdgcn_mfma_f32_16x16x32_bf16(a, b1, acc[g][1], 0, 0, 0);
            }
        }
#pragma unroll
        for (int g = 0; g < 4; ++g) {
            int base0 = ((g * 4 + w) * 64 + (col >> 3) * 16) * 8 + (col & 7);
#pragma unroll
            for (int r = 0; r < 4; ++r) {
                int mrow = quad * 4 + r;
                sM[base0 + mrow * 8]              = f2bf_fast(silu(acc[g][0][r] + bn1A));
                sM[base0 + 2 * 16 * 8 + mrow * 8] = f2bf_fast(silu(acc[g][1][r] + bn1B));
            }
        }
        __syncthreads();

        f32x4 acc2[4][2] = {};
#pragma unroll
        for (int kc = 0; kc < 4; ++kc) {
            bf16x8 b0 = *(const bf16x8*)(Wn2s + ((kc * 8 + nt0)     * 64 + lane) * 8);
            bf16x8 b1 = *(const bf16x8*)(Wn2s + ((kc * 8 + nt0 + 1) * 64 + lane) * 8);
#pragma unroll
            for (int g = 0; g < 4; ++g) {
                bf16x8 a = *(const bf16x8*)(sM + ((g * 4 + kc) * 64 + lane) * 8);
                acc2[g][0] = __builtin_amdgcn_mfma_f32_16x16x32_bf16(a, b0, acc2[g][0], 0, 0, 0);
                acc2[g][1] = __builtin_amdgcn_mfma_f32_16x16x32_bf16(a, b1, acc2[g][1], 0, 0, 0);
            }
        }
#pragma unroll
        for (int g = 0; g < 4; ++g) {
#pragma unroll
            for (int r = 0; r < 4; ++r) {
                int ml2 = g * 16 + quad * 4 + r;
                int node = n0 + ml2;
                if (node < NN) {
                    size_t oi = (size_t)node * 128;
                    float h0 = isf ? ((const float*)hraw)[oi + nA] : bf2f(((const ushort*)hraw)[oi + nA]);
                    float h1 = isf ? ((const float*)hraw)[oi + nB] : bf2f(((const ushort*)hraw)[oi + nB]);
                    float x0 = acc2[g][0][r] + bn2A + h0;
                    float x1 = acc2[g][1][r] + bn2B + h1;
                    if (isf) { outf[oi + nA] = x0; outf[oi + nB] = x1; }
                    else     { outu[oi + nA] = f2bf_fast(x0); outu[oi + nB] = f2bf_fast(x1); }
                }
            }
        }
    }
}

extern "C" void kernel_launch(void* const* d_in, const int* in_sizes, int n_in,
                              void* d_out, int out_size, void* d_ws, size_t ws_size,
                              hipStream_t stream) {
    const void* xz  = d_in[0];
    const void* h   = d_in[1];
    const void* We1 = d_in[2];
    const void* be1 = d_in[3];
    const void* We2 = d_in[4];
    const void* be2 = d_in[5];
    const void* Wn1 = d_in[6];
    const void* bn1 = d_in[7];
    const void* Wn2 = d_in[8];
    const void* bn2 = d_in[9];
    const int*  ei  = (const int*)d_in[10];
    const int* erow = ei;
    const int* ecol = ei + EE;

    char* base = (char*)d_ws;
    size_t cur = 0;
    auto alloc = [&](size_t bytes) { size_t o = cur; cur = (cur + bytes + 255) & ~(size_t)255; return o; };
    int*    flag = (int*)   (base + alloc(16));
    float*  agg  = (float*) (base + alloc((size_t)NN * 128 * 4));
    int*    cntI = (int*)   (base + alloc((size_t)NN * 4));
    ushort* hb   = (ushort*)(base + alloc((size_t)NN * 128 * 2));
    ushort* Pp   = (ushort*)(base + alloc((size_t)NN * 128 * 2));
    ushort* Qq   = (ushort*)(base + alloc((size_t)NN * 128 * 2));
    float*  dist = (float*) (base + alloc((size_t)EE * 4));
    float*  xzf  = (float*) (base + alloc((size_t)NN * 3 * 4 + 16));   // +pad for float4 loads
    ushort* We1s = (ushort*)(base + alloc(32768 * 2));
    ushort* We2s = (ushort*)(base + alloc(16384 * 2));
    ushort* Wn1s = (ushort*)(base + alloc(32768 * 2));
    ushort* Wn2s = (ushort*)(base + alloc(16384 * 2));
    float*  fb   = (float*) (base + alloc(640 * 4));
    ushort* wlb  = (ushort*)(base + alloc(128 * 2));

    // zero agg + cntI (adjacent)
    size_t zbytes = (size_t)((char*)hb - (char*)agg);
    (void)hipMemsetAsync(agg, 0, zbytes, stream);

    detect_kernel<<<1, 256, 0, stream>>>((const ushort*)xz, flag);
    prep_kernel<<<6837, 256, 0, stream>>>(h, xz, erow, flag, hb, xzf, cntI);
    swizzle_misc_kernel<<<49, 256, 0, stream>>>(We1, We2, Wn1, Wn2, be1, be2, bn1, bn2,
                                                flag, We1s, We2s, Wn1s, Wn2s, fb, wlb);
    pq_kernel<<<782, 256, 0, stream>>>(hb, We1s, fb, Pp, Qq);
    dist_kernel<<<(EE + 255) / 256, 256, 0, stream>>>(erow, ecol, xzf, dist);
    edge_kernel<<<1024, 256, 0, stream>>>(Pp, Qq, erow, ecol, dist, We2s, wlb, fb, agg);
    node_kernel<<<782, 256, 0, stream>>>(hb, h, agg, cntI, Wn1s, Wn2s, fb, flag, d_out);
}